// Round 7
// baseline (435.070 us; speedup 1.0000x reference)
//
#include <hip/hip_runtime.h>

#define TE 64
#define THREADS 256
#define XS 136         // u16 LDS stride per row: 128 + 8 pad (conflict-free)
#define T_SM 0.05f
#define MARGIN_FAST 1e-2f   // fp16-Y raw err sigma~1.5e-3, tail 0.0078 observed; 1e-2 ~ 6.7 sigma
#define MARGIN_FB   1e-3f

typedef short s8v __attribute__((ext_vector_type(8)));    // 8 bf16 = 4 VGPRs (MFMA A/B frag)
typedef float f16v __attribute__((ext_vector_type(16)));  // 32x32 C/D frag
typedef unsigned short u16;

__device__ __forceinline__ u16 f2bf(float x) {            // fp32 -> bf16 RNE
    union { float f; unsigned u; } v; v.f = x;
    return (u16)((v.u + 0x7FFFu + ((v.u >> 16) & 1u)) >> 16);
}
__device__ __forceinline__ float bf2f(u16 h) {
    union { unsigned u; float f; } v; v.u = ((unsigned)h) << 16;
    return v.f;
}

// ---- W1 [256,256] f32 -> bf16 hi/lo in B-fragment layout; also zero count ----
// col n, k-group g=k/8 in [0,32): w1t[n*512 + g*16 + j]=hi, [+8]=lo.
__global__ void prep_kernel(const float* __restrict__ W1, u16* __restrict__ w1t,
                            int* __restrict__ count) {
    int t = blockIdx.x * 256 + threadIdx.x;
    if (t == 0) *count = 0;
    if (t < 65536) {
        int n = t & 255, k = t >> 8;
        float w = W1[k * 256 + n];
        u16 h = f2bf(w);
        u16 l = f2bf(w - bf2f(h));
        int g = k >> 3, j = k & 7;
        w1t[n * 512 + g * 16 + j] = h;
        w1t[n * 512 + g * 16 + j + 8] = l;
    }
}

// ============================ FAST PATH ============================
// Dense GEMM: Y[n][0:256]=emb[n]@W1[0:128,:], Y[n][256:512]=emb[n]@W1[128:,:].
// Wave wv owns out-cols [wv*128, wv*128+128); n-tile nt covers cols wv*128 + l31*4 + nt
// (lane-interleaved so each lane owns 4 CONSECUTIVE cols -> packed 8B fp16 stores).
// Frag layouts (m74/m101-verified): A[m=lane&31][k=8*(lane>>5)+j]; C/D col=lane&31,
// row=(reg&3)+8*(reg>>2)+4*(lane>>5).
__global__ __launch_bounds__(THREADS, 2)
void gemm_y_kernel(const float* __restrict__ emb, const u16* __restrict__ w1t,
                   _Float16* __restrict__ Y, int Nn)
{
    __shared__ u16 x_hi[TE * XS];
    __shared__ u16 x_lo[TE * XS];

    const int tid  = threadIdx.x;
    const int base = blockIdx.x * TE;
    const int lane = tid & 63;
    const int wv   = tid >> 6;
    const int l31  = lane & 31;
    const int q8   = lane >> 5;
    const int ge   = tid >> 5;
    const int gseg = tid & 31;

    // stage 64 sequential emb rows (coalesced), split to bf16 hi/lo
    #pragma unroll
    for (int q = 0; q < 8; ++q) {
        int node = base + ge + 8 * q;
        if (node >= Nn) node = Nn - 1;
        float4 v = ((const float4*)(emb + (size_t)node * 128))[gseg];
        u16 h0 = f2bf(v.x), h1 = f2bf(v.y), h2 = f2bf(v.z), h3 = f2bf(v.w);
        u16 l0 = f2bf(v.x - bf2f(h0)), l1 = f2bf(v.y - bf2f(h1));
        u16 l2 = f2bf(v.z - bf2f(h2)), l3 = f2bf(v.w - bf2f(h3));
        int off = (ge + 8 * q) * XS + gseg * 4;
        *(uint2*)&x_hi[off] = make_uint2((unsigned)h0 | ((unsigned)h1 << 16),
                                         (unsigned)h2 | ((unsigned)h3 << 16));
        *(uint2*)&x_lo[off] = make_uint2((unsigned)l0 | ((unsigned)l1 << 16),
                                         (unsigned)l2 | ((unsigned)l3 << 16));
    }
    __syncthreads();

    f16v acc[2][4];
    #pragma unroll
    for (int mt = 0; mt < 2; ++mt)
        #pragma unroll
        for (int nt = 0; nt < 4; ++nt)
            acc[mt][nt] = (f16v)0.f;

    const int arow0 = l31 * XS;
    const int arow1 = (32 + l31) * XS;
    const u16* bb[4];
    #pragma unroll
    for (int nt = 0; nt < 4; ++nt) {
        int ncol = wv * 128 + l31 * 4 + nt;           // lane-interleaved col mapping
        int p = ncol & 255;
        int gbase = (ncol >> 8) * 16;                 // Yr: g0..15, Yc: g16..31
        bb[nt] = w1t + (size_t)p * 512 + (gbase + q8) * 16;
    }

    #pragma unroll
    for (int sl = 0; sl < 8; ++sl) {                  // K=128 in 8 ksteps of 16
        const int aoff = 16 * sl + 8 * q8;
        s8v ah0 = *(const s8v*)&x_hi[arow0 + aoff];
        s8v ah1 = *(const s8v*)&x_hi[arow1 + aoff];
        s8v al0 = *(const s8v*)&x_lo[arow0 + aoff];
        s8v al1 = *(const s8v*)&x_lo[arow1 + aoff];
        #pragma unroll
        for (int nt = 0; nt < 4; ++nt) {
            const u16* bp = bb[nt] + sl * 32;
            s8v bh = *(const s8v*)bp;
            s8v bl = *(const s8v*)(bp + 8);
            acc[0][nt] = __builtin_amdgcn_mfma_f32_32x32x16_bf16(ah0, bh, acc[0][nt], 0, 0, 0);
            acc[0][nt] = __builtin_amdgcn_mfma_f32_32x32x16_bf16(ah0, bl, acc[0][nt], 0, 0, 0);
            acc[0][nt] = __builtin_amdgcn_mfma_f32_32x32x16_bf16(al0, bh, acc[0][nt], 0, 0, 0);
            acc[1][nt] = __builtin_amdgcn_mfma_f32_32x32x16_bf16(ah1, bh, acc[1][nt], 0, 0, 0);
            acc[1][nt] = __builtin_amdgcn_mfma_f32_32x32x16_bf16(ah1, bl, acc[1][nt], 0, 0, 0);
            acc[1][nt] = __builtin_amdgcn_mfma_f32_32x32x16_bf16(al1, bh, acc[1][nt], 0, 0, 0);
        }
    }

    // epilogue: pack 4 consecutive cols -> one 8B store (32 stores/thread, was 128x2B)
    #pragma unroll
    for (int mt = 0; mt < 2; ++mt) {
        #pragma unroll
        for (int r = 0; r < 16; ++r) {
            int node = base + mt * 32 + (r & 3) + 8 * (r >> 2) + 4 * q8;
            if (node < Nn) {
                _Float16 pk[4] = {(_Float16)acc[mt][0][r], (_Float16)acc[mt][1][r],
                                  (_Float16)acc[mt][2][r], (_Float16)acc[mt][3][r]};
                *(uint2*)(Y + (size_t)node * 512 + wv * 128 + l31 * 4) = *(uint2*)pk;
            }
        }
    }
}

// Edge pass: raw(e) = relu(Yr[row]+Yc[col]+b1) . W2 + b2. Half-wave per edge,
// 2 edges per half-wave per iteration (4 x 16B loads in flight).
__global__ __launch_bounds__(256, 8)
void edge_kernel(const _Float16* __restrict__ Y, const int* __restrict__ ei,
                 const float* __restrict__ b1, const float* __restrict__ W2,
                 const float* __restrict__ b2p, float* __restrict__ out,
                 int* __restrict__ count, int* __restrict__ list, int cap, int E)
{
    const int tid = threadIdx.x;
    const int l31 = tid & 31;
    const int q8  = (tid & 63) >> 5;
    const int gw  = (blockIdx.x * 256 + tid) >> 6;
    const int nw  = (gridDim.x * 256) >> 6;

    float b1v[8], w2v[8];
    #pragma unroll
    for (int j = 0; j < 8; ++j) {
        b1v[j] = b1[8 * l31 + j];
        w2v[j] = W2[8 * l31 + j];
    }
    const float b2s = b2p[0];
    const int nquad = (E + 3) >> 2;

    for (int qd = gw; qd < nquad; qd += nw) {
        int eA = 4 * qd + q8;
        int eB = eA + 2;
        bool vA = eA < E, vB = eB < E;
        int esA = vA ? eA : 0, esB = vB ? eB : 0;
        int rowA = ei[esA], colA = ei[E + esA];    // broadcast across half-wave
        int rowB = ei[esB], colB = ei[E + esB];
        union { uint4 u; _Float16 h[8]; } yrA, ycA, yrB, ycB;
        yrA.u = *(const uint4*)(Y + (size_t)rowA * 512 + 8 * l31);
        ycA.u = *(const uint4*)(Y + (size_t)colA * 512 + 256 + 8 * l31);
        yrB.u = *(const uint4*)(Y + (size_t)rowB * 512 + 8 * l31);
        ycB.u = *(const uint4*)(Y + (size_t)colB * 512 + 256 + 8 * l31);
        float pA = 0.f, pB = 0.f;
        #pragma unroll
        for (int j = 0; j < 8; ++j) {
            float hA = (float)yrA.h[j] + (float)ycA.h[j] + b1v[j];
            float hB = (float)yrB.h[j] + (float)ycB.h[j] + b1v[j];
            pA += (hA > 0.f ? hA : 0.f) * w2v[j];
            pB += (hB > 0.f ? hB : 0.f) * w2v[j];
        }
        pA += __shfl_xor(pA, 1);  pB += __shfl_xor(pB, 1);
        pA += __shfl_xor(pA, 2);  pB += __shfl_xor(pB, 2);
        pA += __shfl_xor(pA, 4);  pB += __shfl_xor(pB, 4);
        pA += __shfl_xor(pA, 8);  pB += __shfl_xor(pB, 8);
        pA += __shfl_xor(pA, 16); pB += __shfl_xor(pB, 16);  // stays in 32-lane half
        if (l31 == 0) {
            if (vA) {
                float raw = pA + b2s;
                out[eA] = (raw < T_SM) ? 0.f : raw;
                if (fabsf(raw - T_SM) < MARGIN_FAST) {
                    int pos = atomicAdd(count, 1);
                    if (pos < cap) list[pos] = eA;
                }
            }
            if (vB) {
                float raw = pB + b2s;
                out[eB] = (raw < T_SM) ? 0.f : raw;
                if (fabsf(raw - T_SM) < MARGIN_FAST) {
                    int pos = atomicAdd(count, 1);
                    if (pos < cap) list[pos] = eB;
                }
            }
        }
    }
}

// ============================ FALLBACK PATH (R5, proven) ============================
__global__ __launch_bounds__(THREADS, 3)
void linkmlp_mfma(const float* __restrict__ emb, const int* __restrict__ ei,
                  const u16* __restrict__ w1t, const float* __restrict__ b1,
                  const float* __restrict__ W2, const float* __restrict__ b2p,
                  float* __restrict__ out, int* __restrict__ count,
                  int* __restrict__ list, int cap, int E)
{
    __shared__ u16 x_hi[TE * XS];
    __shared__ u16 x_lo[TE * XS];
    __shared__ float red[4][TE];
    __shared__ int s_idx[2][TE];

    const int tid  = threadIdx.x;
    const int base = blockIdx.x * TE;
    const int lane = tid & 63;
    const int wv   = tid >> 6;
    const int l31  = lane & 31;
    const int q8   = lane >> 5;
    const int ge   = tid >> 5;
    const int gseg = tid & 31;

    if (tid < TE) { int e = base + tid; s_idx[0][tid] = (e < E) ? ei[e] : 0; }
    else if (tid < 2 * TE) { int t2 = tid - TE; int e = base + t2; s_idx[1][t2] = (e < E) ? ei[E + e] : 0; }
    __syncthreads();

    float b1v[2], w2v[2];
    #pragma unroll
    for (int nt = 0; nt < 2; ++nt) {
        int c = wv * 64 + nt * 32 + l31;
        b1v[nt] = b1[c];
        w2v[nt] = W2[c];
    }
    const float b2s = b2p[0];

    f16v acc[2][2];
    #pragma unroll
    for (int mt = 0; mt < 2; ++mt)
        #pragma unroll
        for (int nt = 0; nt < 2; ++nt)
            acc[mt][nt] = (f16v)0.f;

    float4 gv[8];
    auto issue_gather = [&](int half) {
        #pragma unroll
        for (int q = 0; q < 8; ++q) {
            int node = s_idx[half][ge + 8 * q];
            gv[q] = ((const float4*)(emb + (size_t)node * 128))[gseg];
        }
    };
    auto write_gather = [&]() {
        #pragma unroll
        for (int q = 0; q < 8; ++q) {
            float4 v = gv[q];
            u16 h0 = f2bf(v.x), h1 = f2bf(v.y), h2 = f2bf(v.z), h3 = f2bf(v.w);
            u16 l0 = f2bf(v.x - bf2f(h0)), l1 = f2bf(v.y - bf2f(h1));
            u16 l2 = f2bf(v.z - bf2f(h2)), l3 = f2bf(v.w - bf2f(h3));
            int off = (ge + 8 * q) * XS + gseg * 4;
            *(uint2*)&x_hi[off] = make_uint2((unsigned)h0 | ((unsigned)h1 << 16),
                                             (unsigned)h2 | ((unsigned)h3 << 16));
            *(uint2*)&x_lo[off] = make_uint2((unsigned)l0 | ((unsigned)l1 << 16),
                                             (unsigned)l2 | ((unsigned)l3 << 16));
        }
    };

    issue_gather(0);
    write_gather();
    __syncthreads();

    #pragma unroll
    for (int half = 0; half < 2; ++half) {
        const int arow0 = l31 * XS;
        const int arow1 = (32 + l31) * XS;
        const u16* bbase0 = w1t + (size_t)(wv * 64 + l31) * 512 + (half * 16 + q8) * 16;
        const u16* bbase1 = bbase0 + 32 * 512;
        if (half == 0) issue_gather(1);

        auto kstep = [&](int sl) {
            const int aoff = 16 * sl + 8 * q8;
            s8v ah0 = *(const s8v*)&x_hi[arow0 + aoff];
            s8v ah1 = *(const s8v*)&x_hi[arow1 + aoff];
            s8v al0 = *(const s8v*)&x_lo[arow0 + aoff];
            s8v al1 = *(const s8v*)&x_lo[arow1 + aoff];
            const u16* bp0 = bbase0 + sl * 32;
            const u16* bp1 = bbase1 + sl * 32;
            s8v bh0 = *(const s8v*)bp0;  s8v bl0 = *(const s8v*)(bp0 + 8);
            s8v bh1 = *(const s8v*)bp1;  s8v bl1 = *(const s8v*)(bp1 + 8);
            acc[0][0] = __builtin_amdgcn_mfma_f32_32x32x16_bf16(ah0, bh0, acc[0][0], 0, 0, 0);
            acc[0][0] = __builtin_amdgcn_mfma_f32_32x32x16_bf16(ah0, bl0, acc[0][0], 0, 0, 0);
            acc[0][0] = __builtin_amdgcn_mfma_f32_32x32x16_bf16(al0, bh0, acc[0][0], 0, 0, 0);
            acc[1][0] = __builtin_amdgcn_mfma_f32_32x32x16_bf16(ah1, bh0, acc[1][0], 0, 0, 0);
            acc[1][0] = __builtin_amdgcn_mfma_f32_32x32x16_bf16(ah1, bl0, acc[1][0], 0, 0, 0);
            acc[1][0] = __builtin_amdgcn_mfma_f32_32x32x16_bf16(al1, bh0, acc[1][0], 0, 0, 0);
            acc[0][1] = __builtin_amdgcn_mfma_f32_32x32x16_bf16(ah0, bh1, acc[0][1], 0, 0, 0);
            acc[0][1] = __builtin_amdgcn_mfma_f32_32x32x16_bf16(ah0, bl1, acc[0][1], 0, 0, 0);
            acc[0][1] = __builtin_amdgcn_mfma_f32_32x32x16_bf16(al0, bh1, acc[0][1], 0, 0, 0);
            acc[1][1] = __builtin_amdgcn_mfma_f32_32x32x16_bf16(ah1, bh1, acc[1][1], 0, 0, 0);
            acc[1][1] = __builtin_amdgcn_mfma_f32_32x32x16_bf16(ah1, bl1, acc[1][1], 0, 0, 0);
            acc[1][1] = __builtin_amdgcn_mfma_f32_32x32x16_bf16(al1, bh1, acc[1][1], 0, 0, 0);
        };

        kstep(0); kstep(1); kstep(2); kstep(3);
        kstep(4); kstep(5); kstep(6); kstep(7);

        if (half == 0) {
            __syncthreads();
            write_gather();
            __syncthreads();
        }
    }

    #pragma unroll
    for (int mt = 0; mt < 2; ++mt) {
        #pragma unroll
        for (int r = 0; r < 16; ++r) {
            float h0 = acc[mt][0][r] + b1v[0];
            float h1 = acc[mt][1][r] + b1v[1];
            float pp = (h0 > 0.f ? h0 : 0.f) * w2v[0] + (h1 > 0.f ? h1 : 0.f) * w2v[1];
            pp += __shfl_xor(pp, 1);  pp += __shfl_xor(pp, 2);
            pp += __shfl_xor(pp, 4);  pp += __shfl_xor(pp, 8);
            pp += __shfl_xor(pp, 16);
            if (l31 == 0)
                red[wv][mt * 32 + (r & 3) + 8 * (r >> 2) + 4 * q8] = pp;
        }
    }
    __syncthreads();

    if (tid < TE) {
        int eg = base + tid;
        if (eg < E) {
            float raw = red[0][tid] + red[1][tid] + red[2][tid] + red[3][tid] + b2s;
            out[eg] = (raw < T_SM) ? 0.f : raw;
            if (fabsf(raw - T_SM) < MARGIN_FB) {
                int pos = atomicAdd(count, 1);
                if (pos < cap) list[pos] = eg;
            }
        }
    }
}

// ---- exact fp32 recompute of near-threshold edges (one wave/edge) ----
__global__ __launch_bounds__(256, 4)
void fixup_kernel(const float* __restrict__ emb, const int* __restrict__ ei,
                  const float* __restrict__ W1, const float* __restrict__ b1,
                  const float* __restrict__ W2, const float* __restrict__ b2p,
                  const int* __restrict__ count, const int* __restrict__ list,
                  float* __restrict__ out, int E, int cap)
{
    int cnt = *count; if (cnt > cap) cnt = cap;
    const int lane = threadIdx.x & 63;
    const int gw = (blockIdx.x * 256 + threadIdx.x) >> 6;
    const int nw = (gridDim.x * 256) >> 6;
    for (int i = gw; i < cnt; i += nw) {
        int e = list[i];
        int rn = ei[e], cn = ei[E + e];
        const float* src = (lane < 32) ? emb + (size_t)rn * 128 + lane * 4
                                       : emb + (size_t)cn * 128 + (lane - 32) * 4;
        float4 xv = *(const float4*)src;
        float hacc[4] = {0.f, 0.f, 0.f, 0.f};
        for (int k0 = 0; k0 < 256; k0 += 4) {
            int sl = k0 >> 2;
            float x0 = __shfl(xv.x, sl), x1 = __shfl(xv.y, sl);
            float x2 = __shfl(xv.z, sl), x3 = __shfl(xv.w, sl);
            #pragma unroll
            for (int c = 0; c < 4; ++c) {
                int col = lane + 64 * c;
                hacc[c] += x0 * W1[(k0 + 0) * 256 + col] + x1 * W1[(k0 + 1) * 256 + col]
                         + x2 * W1[(k0 + 2) * 256 + col] + x3 * W1[(k0 + 3) * 256 + col];
            }
        }
        float p = 0.f;
        #pragma unroll
        for (int c = 0; c < 4; ++c) {
            float h = hacc[c] + b1[lane + 64 * c];
            p += (h > 0.f ? h : 0.f) * W2[lane + 64 * c];
        }
        p += __shfl_xor(p, 1);  p += __shfl_xor(p, 2);  p += __shfl_xor(p, 4);
        p += __shfl_xor(p, 8);  p += __shfl_xor(p, 16); p += __shfl_xor(p, 32);
        if (lane == 0) {
            float raw = p + b2p[0];
            out[e] = (raw < T_SM) ? 0.f : raw;
        }
    }
}

extern "C" void kernel_launch(void* const* d_in, const int* in_sizes, int n_in,
                              void* d_out, int out_size, void* d_ws, size_t ws_size,
                              hipStream_t stream) {
    const float* emb = (const float*)d_in[0];
    const int*   ei  = (const int*)  d_in[1];
    const float* W1  = (const float*)d_in[2];
    const float* b1  = (const float*)d_in[3];
    const float* W2  = (const float*)d_in[4];
    const float* b2  = (const float*)d_in[5];
    float* out = (float*)d_out;
    const int E  = out_size;
    const int Nn = in_sizes[0] / 128;

    const size_t yBytes = (size_t)Nn * 512 * sizeof(_Float16);   // 102.4 MB @ N=100000
    const size_t fastNeed = yBytes + 262144 + 64 + 65536;

    if (ws_size >= fastNeed) {
        // fast path: factorized Y-table
        _Float16* Y = (_Float16*)d_ws;
        u16* w1t   = (u16*)((char*)d_ws + yBytes);
        int* count = (int*)((char*)d_ws + yBytes + 262144);
        int* list  = (int*)((char*)d_ws + yBytes + 262208);
        int cap = (int)((ws_size - (yBytes + 262208)) / 4);
        if (cap > E) cap = E;

        hipLaunchKernelGGL(prep_kernel, dim3(256), dim3(256), 0, stream, W1, w1t, count);
        hipLaunchKernelGGL(gemm_y_kernel, dim3((Nn + TE - 1) / TE), dim3(THREADS), 0, stream,
                           emb, w1t, Y, Nn);
        hipLaunchKernelGGL(edge_kernel, dim3(4096), dim3(256), 0, stream,
                           Y, ei, b1, W2, b2, out, count, list, cap, E);
        hipLaunchKernelGGL(fixup_kernel, dim3(1024), dim3(256), 0, stream,
                           emb, ei, W1, b1, W2, b2, count, list, out, E, cap);
    } else {
        // fallback: R5 fused edge-GEMM (proven)
        u16* w1t   = (u16*)d_ws;
        int* count = (int*)((char*)d_ws + 262144);
        int* list  = (int*)((char*)d_ws + 262208);
        long avail = (long)ws_size - 262208;
        int cap = (avail > 4) ? (int)(avail / 4) : 0;
        if (cap > E) cap = E;

        hipLaunchKernelGGL(prep_kernel, dim3(256), dim3(256), 0, stream, W1, w1t, count);
        hipLaunchKernelGGL(linkmlp_mfma, dim3((E + TE - 1) / TE), dim3(THREADS), 0, stream,
                           emb, ei, w1t, b1, W2, b2, out, count, list, cap, E);
        hipLaunchKernelGGL(fixup_kernel, dim3(128), dim3(256), 0, stream,
                           emb, ei, W1, b1, W2, b2, count, list, out, E, cap);
    }
}

// Round 9
// 415.556 us; speedup vs baseline: 1.0470x; 1.0470x over previous
//
#include <hip/hip_runtime.h>

#define TE 64
#define THREADS 256
#define XS 136         // u16 LDS stride per row: 128 + 8 pad (conflict-free)
#define T_SM 0.05f
#define MARGIN_FAST 1e-2f   // absmax observed 0.0078 < margin -> no threshold flips possible
#define MARGIN_FB   1e-3f

typedef short s8v __attribute__((ext_vector_type(8)));    // 8 bf16 = 4 VGPRs (MFMA A/B frag)
typedef float f16v __attribute__((ext_vector_type(16)));  // 32x32 C/D frag
typedef unsigned short u16;

__device__ __forceinline__ u16 f2bf(float x) {            // fp32 -> bf16 RNE
    union { float f; unsigned u; } v; v.f = x;
    return (u16)((v.u + 0x7FFFu + ((v.u >> 16) & 1u)) >> 16);
}
__device__ __forceinline__ float bf2f(u16 h) {
    union { unsigned u; float f; } v; v.u = ((unsigned)h) << 16;
    return v.f;
}

// ---- fast-path prep: W1 [256,256] f32 -> TRANSPOSED fragment planes ----
// hi plane: w1tT[g*2048 + n*8 + j], lo plane at +65536 (u16 units); g=k>>3, j=k&7.
// B-frag load for (g, n=..+l31) is then lane-consecutive 16B -> fully coalesced.
__global__ void prep_kernelT(const float* __restrict__ W1, u16* __restrict__ w1tT,
                             int* __restrict__ count) {
    int t = blockIdx.x * 256 + threadIdx.x;
    if (t == 0) *count = 0;
    if (t < 65536) {
        int n = t & 255, k = t >> 8;
        float w = W1[k * 256 + n];
        u16 h = f2bf(w);
        u16 l = f2bf(w - bf2f(h));
        int g = k >> 3, j = k & 7;
        w1tT[g * 2048 + n * 8 + j] = h;
        w1tT[65536 + g * 2048 + n * 8 + j] = l;
    }
}

// ---- fallback prep: old per-n fragment layout (kept for the fallback kernel) ----
__global__ void prep_kernel(const float* __restrict__ W1, u16* __restrict__ w1t,
                            int* __restrict__ count) {
    int t = blockIdx.x * 256 + threadIdx.x;
    if (t == 0) *count = 0;
    if (t < 65536) {
        int n = t & 255, k = t >> 8;
        float w = W1[k * 256 + n];
        u16 h = f2bf(w);
        u16 l = f2bf(w - bf2f(h));
        int g = k >> 3, j = k & 7;
        w1t[n * 512 + g * 16 + j] = h;
        w1t[n * 512 + g * 16 + j + 8] = l;
    }
}

// ============================ FAST PATH ============================
// Dense GEMM: Y[n][0:256]=emb[n]@W1[0:128,:], Y[n][256:512]=emb[n]@W1[128:,:].
// Wave wv owns out-cols [wv*128, wv*128+128) as 4 n-tiles of 32 (col = ..+l31).
// Frag layouts (m74/m101-verified): A[m=lane&31][k=8*(lane>>5)+j]; C/D col=lane&31,
// row=(reg&3)+8*(reg>>2)+4*(lane>>5).
// Epilogue goes acc -> LDS (node-major, pad-520) -> coalesced dwordx4 stores.
// R8 BUG FIXED: smem must hold the epilogue view (64*520 u16 = 66560 B), not just
// the x-staging view (2*64*136 u16 = 34816 B). R8 declared the smaller one ->
// epilogue wrote past the LDS block -> absmax 1.6.
__global__ __launch_bounds__(THREADS, 2)
void gemm_y_kernel(const float* __restrict__ emb, const u16* __restrict__ w1tT,
                   _Float16* __restrict__ Y, int Nn)
{
    __shared__ u16 smem[TE * 520];           // 66560 B union: x staging | epilogue
    u16* x_hi = smem;                        // x view: [0, 2*TE*XS) = 34816 B
    u16* x_lo = smem + TE * XS;
    u16* ep   = smem;                        // epilogue view: 64 nodes x 520 u16

    const int tid  = threadIdx.x;
    const int base = blockIdx.x * TE;
    const int lane = tid & 63;
    const int wv   = tid >> 6;
    const int l31  = lane & 31;
    const int q8   = lane >> 5;
    const int ge   = tid >> 5;
    const int gseg = tid & 31;

    // stage 64 sequential emb rows (coalesced), split to bf16 hi/lo
    #pragma unroll
    for (int q = 0; q < 8; ++q) {
        int node = base + ge + 8 * q;
        if (node >= Nn) node = Nn - 1;
        float4 v = ((const float4*)(emb + (size_t)node * 128))[gseg];
        u16 h0 = f2bf(v.x), h1 = f2bf(v.y), h2 = f2bf(v.z), h3 = f2bf(v.w);
        u16 l0 = f2bf(v.x - bf2f(h0)), l1 = f2bf(v.y - bf2f(h1));
        u16 l2 = f2bf(v.z - bf2f(h2)), l3 = f2bf(v.w - bf2f(h3));
        int off = (ge + 8 * q) * XS + gseg * 4;
        *(uint2*)&x_hi[off] = make_uint2((unsigned)h0 | ((unsigned)h1 << 16),
                                         (unsigned)h2 | ((unsigned)h3 << 16));
        *(uint2*)&x_lo[off] = make_uint2((unsigned)l0 | ((unsigned)l1 << 16),
                                         (unsigned)l2 | ((unsigned)l3 << 16));
    }
    __syncthreads();

    f16v acc[2][4];
    #pragma unroll
    for (int mt = 0; mt < 2; ++mt)
        #pragma unroll
        for (int nt = 0; nt < 4; ++nt)
            acc[mt][nt] = (f16v)0.f;

    const int arow0 = l31 * XS;
    const int arow1 = (32 + l31) * XS;
    int noff[4];                                   // n-part of B addr, per n-tile
    #pragma unroll
    for (int nt = 0; nt < 4; ++nt)
        noff[nt] = ((wv * 128 + nt * 32 + l31) & 255) * 8;
    const int gbase = (wv >> 1) * 16;              // wv 0,1 -> Yr (g0..15); wv 2,3 -> Yc

    #pragma unroll
    for (int sl = 0; sl < 8; ++sl) {               // K=128 in 8 ksteps of 16
        const int aoff = 16 * sl + 8 * q8;
        s8v ah0 = *(const s8v*)&x_hi[arow0 + aoff];
        s8v ah1 = *(const s8v*)&x_hi[arow1 + aoff];
        s8v al0 = *(const s8v*)&x_lo[arow0 + aoff];
        s8v al1 = *(const s8v*)&x_lo[arow1 + aoff];
        const u16* gb = w1tT + (gbase + 2 * sl + q8) * 2048;
        #pragma unroll
        for (int nt = 0; nt < 4; ++nt) {
            s8v bh = *(const s8v*)(gb + noff[nt]);          // coalesced 512B/half-wave
            s8v bl = *(const s8v*)(gb + 65536 + noff[nt]);
            acc[0][nt] = __builtin_amdgcn_mfma_f32_32x32x16_bf16(ah0, bh, acc[0][nt], 0, 0, 0);
            acc[0][nt] = __builtin_amdgcn_mfma_f32_32x32x16_bf16(ah0, bl, acc[0][nt], 0, 0, 0);
            acc[0][nt] = __builtin_amdgcn_mfma_f32_32x32x16_bf16(al0, bh, acc[0][nt], 0, 0, 0);
            acc[1][nt] = __builtin_amdgcn_mfma_f32_32x32x16_bf16(ah1, bh, acc[1][nt], 0, 0, 0);
            acc[1][nt] = __builtin_amdgcn_mfma_f32_32x32x16_bf16(ah1, bl, acc[1][nt], 0, 0, 0);
            acc[1][nt] = __builtin_amdgcn_mfma_f32_32x32x16_bf16(al1, bh, acc[1][nt], 0, 0, 0);
        }
    }

    // ---- epilogue: acc -> LDS (node-major, row stride 520 u16) ----
    __syncthreads();                               // all x reads done; smem reused
    #pragma unroll
    for (int mt = 0; mt < 2; ++mt) {
        #pragma unroll
        for (int nt = 0; nt < 4; ++nt) {
            int c = wv * 128 + nt * 32 + l31;
            #pragma unroll
            for (int r = 0; r < 16; ++r) {
                int node64 = mt * 32 + (r & 3) + 8 * (r >> 2) + 4 * q8;
                ep[node64 * 520 + c] = (u16)__builtin_bit_cast(unsigned short, (_Float16)acc[mt][nt][r]);
            }
        }
    }
    __syncthreads();

    // LDS -> global: 4096 16B chunks, 16 per thread, fully coalesced
    #pragma unroll
    for (int i = 0; i < 16; ++i) {
        int ch = tid + 256 * i;
        int node64 = ch >> 6;
        int cg = ch & 63;
        int gnode = base + node64;
        if (gnode < Nn) {
            uint4 v = *(const uint4*)&ep[node64 * 520 + 8 * cg];   // b128, aligned (1040B row stride)
            *(uint4*)(Y + (size_t)gnode * 512 + 8 * cg) = v;
        }
    }
}

// Edge pass (R6-proven config): raw(e) = relu(Yr[row]+Yc[col]+b1) . W2 + b2.
// Half-wave per edge; lane covers 8 of 256 h-cols; 2x 16B loads from L3-resident Y.
__global__ __launch_bounds__(256, 6)
void edge_kernel(const _Float16* __restrict__ Y, const int* __restrict__ ei,
                 const float* __restrict__ b1, const float* __restrict__ W2,
                 const float* __restrict__ b2p, float* __restrict__ out,
                 int* __restrict__ count, int* __restrict__ list, int cap, int E)
{
    const int tid = threadIdx.x;
    const int l31 = tid & 31;
    const int q8  = (tid & 63) >> 5;
    const int gw  = (blockIdx.x * 256 + tid) >> 6;
    const int nw  = (gridDim.x * 256) >> 6;

    float b1v[8], w2v[8];
    #pragma unroll
    for (int j = 0; j < 8; ++j) {
        b1v[j] = b1[8 * l31 + j];
        w2v[j] = W2[8 * l31 + j];
    }
    const float b2s = b2p[0];
    const int npairs = (E + 1) >> 1;

    for (int pair = gw; pair < npairs; pair += nw) {
        int e = 2 * pair + q8;
        bool valid = e < E;
        int es = valid ? e : 0;
        int row = ei[es], col = ei[E + es];       // same addr across half-wave: broadcast
        union { uint4 u; _Float16 h[8]; } yr, yc;
        yr.u = *(const uint4*)(Y + (size_t)row * 512 + 8 * l31);
        yc.u = *(const uint4*)(Y + (size_t)col * 512 + 256 + 8 * l31);
        float p = 0.f;
        #pragma unroll
        for (int j = 0; j < 8; ++j) {
            float h = (float)yr.h[j] + (float)yc.h[j] + b1v[j];
            p += (h > 0.f ? h : 0.f) * w2v[j];
        }
        p += __shfl_xor(p, 1);  p += __shfl_xor(p, 2);  p += __shfl_xor(p, 4);
        p += __shfl_xor(p, 8);  p += __shfl_xor(p, 16);   // stays within 32-lane half
        if (l31 == 0 && valid) {
            float raw = p + b2s;
            out[e] = (raw < T_SM) ? 0.f : raw;
            if (fabsf(raw - T_SM) < MARGIN_FAST) {
                int pos = atomicAdd(count, 1);
                if (pos < cap) list[pos] = e;
            }
        }
    }
}

// ============================ FALLBACK PATH (R5, proven) ============================
__global__ __launch_bounds__(THREADS, 3)
void linkmlp_mfma(const float* __restrict__ emb, const int* __restrict__ ei,
                  const u16* __restrict__ w1t, const float* __restrict__ b1,
                  const float* __restrict__ W2, const float* __restrict__ b2p,
                  float* __restrict__ out, int* __restrict__ count,
                  int* __restrict__ list, int cap, int E)
{
    __shared__ u16 x_hi[TE * XS];
    __shared__ u16 x_lo[TE * XS];
    __shared__ float red[4][TE];
    __shared__ int s_idx[2][TE];

    const int tid  = threadIdx.x;
    const int base = blockIdx.x * TE;
    const int lane = tid & 63;
    const int wv   = tid >> 6;
    const int l31  = lane & 31;
    const int q8   = lane >> 5;
    const int ge   = tid >> 5;
    const int gseg = tid & 31;

    if (tid < TE) { int e = base + tid; s_idx[0][tid] = (e < E) ? ei[e] : 0; }
    else if (tid < 2 * TE) { int t2 = tid - TE; int e = base + t2; s_idx[1][t2] = (e < E) ? ei[E + e] : 0; }
    __syncthreads();

    float b1v[2], w2v[2];
    #pragma unroll
    for (int nt = 0; nt < 2; ++nt) {
        int c = wv * 64 + nt * 32 + l31;
        b1v[nt] = b1[c];
        w2v[nt] = W2[c];
    }
    const float b2s = b2p[0];

    f16v acc[2][2];
    #pragma unroll
    for (int mt = 0; mt < 2; ++mt)
        #pragma unroll
        for (int nt = 0; nt < 2; ++nt)
            acc[mt][nt] = (f16v)0.f;

    float4 gv[8];
    auto issue_gather = [&](int half) {
        #pragma unroll
        for (int q = 0; q < 8; ++q) {
            int node = s_idx[half][ge + 8 * q];
            gv[q] = ((const float4*)(emb + (size_t)node * 128))[gseg];
        }
    };
    auto write_gather = [&]() {
        #pragma unroll
        for (int q = 0; q < 8; ++q) {
            float4 v = gv[q];
            u16 h0 = f2bf(v.x), h1 = f2bf(v.y), h2 = f2bf(v.z), h3 = f2bf(v.w);
            u16 l0 = f2bf(v.x - bf2f(h0)), l1 = f2bf(v.y - bf2f(h1));
            u16 l2 = f2bf(v.z - bf2f(h2)), l3 = f2bf(v.w - bf2f(h3));
            int off = (ge + 8 * q) * XS + gseg * 4;
            *(uint2*)&x_hi[off] = make_uint2((unsigned)h0 | ((unsigned)h1 << 16),
                                             (unsigned)h2 | ((unsigned)h3 << 16));
            *(uint2*)&x_lo[off] = make_uint2((unsigned)l0 | ((unsigned)l1 << 16),
                                             (unsigned)l2 | ((unsigned)l3 << 16));
        }
    };

    issue_gather(0);
    write_gather();
    __syncthreads();

    #pragma unroll
    for (int half = 0; half < 2; ++half) {
        const int arow0 = l31 * XS;
        const int arow1 = (32 + l31) * XS;
        const u16* bbase0 = w1t + (size_t)(wv * 64 + l31) * 512 + (half * 16 + q8) * 16;
        const u16* bbase1 = bbase0 + 32 * 512;
        if (half == 0) issue_gather(1);

        auto kstep = [&](int sl) {
            const int aoff = 16 * sl + 8 * q8;
            s8v ah0 = *(const s8v*)&x_hi[arow0 + aoff];
            s8v ah1 = *(const s8v*)&x_hi[arow1 + aoff];
            s8v al0 = *(const s8v*)&x_lo[arow0 + aoff];
            s8v al1 = *(const s8v*)&x_lo[arow1 + aoff];
            const u16* bp0 = bbase0 + sl * 32;
            const u16* bp1 = bbase1 + sl * 32;
            s8v bh0 = *(const s8v*)bp0;  s8v bl0 = *(const s8v*)(bp0 + 8);
            s8v bh1 = *(const s8v*)bp1;  s8v bl1 = *(const s8v*)(bp1 + 8);
            acc[0][0] = __builtin_amdgcn_mfma_f32_32x32x16_bf16(ah0, bh0, acc[0][0], 0, 0, 0);
            acc[0][0] = __builtin_amdgcn_mfma_f32_32x32x16_bf16(ah0, bl0, acc[0][0], 0, 0, 0);
            acc[0][0] = __builtin_amdgcn_mfma_f32_32x32x16_bf16(al0, bh0, acc[0][0], 0, 0, 0);
            acc[1][0] = __builtin_amdgcn_mfma_f32_32x32x16_bf16(ah1, bh0, acc[1][0], 0, 0, 0);
            acc[1][0] = __builtin_amdgcn_mfma_f32_32x32x16_bf16(ah1, bl0, acc[1][0], 0, 0, 0);
            acc[1][0] = __builtin_amdgcn_mfma_f32_32x32x16_bf16(al1, bh0, acc[1][0], 0, 0, 0);
            acc[0][1] = __builtin_amdgcn_mfma_f32_32x32x16_bf16(ah0, bh1, acc[0][1], 0, 0, 0);
            acc[0][1] = __builtin_amdgcn_mfma_f32_32x32x16_bf16(ah0, bl1, acc[0][1], 0, 0, 0);
            acc[0][1] = __builtin_amdgcn_mfma_f32_32x32x16_bf16(al0, bh1, acc[0][1], 0, 0, 0);
            acc[1][1] = __builtin_amdgcn_mfma_f32_32x32x16_bf16(ah1, bh1, acc[1][1], 0, 0, 0);
            acc[1][1] = __builtin_amdgcn_mfma_f32_32x32x16_bf16(ah1, bl1, acc[1][1], 0, 0, 0);
            acc[1][1] = __builtin_amdgcn_mfma_f32_32x32x16_bf16(al1, bh1, acc[1][1], 0, 0, 0);
        };

        kstep(0); kstep(1); kstep(2); kstep(3);
        kstep(4); kstep(5); kstep(6); kstep(7);

        if (half == 0) {
            __syncthreads();
            write_gather();
            __syncthreads();
        }
    }

    #pragma unroll
    for (int mt = 0; mt < 2; ++mt) {
        #pragma unroll
        for (int r = 0; r < 16; ++r) {
            float h0 = acc[mt][0][r] + b1v[0];
            float h1 = acc[mt][1][r] + b1v[1];
            float pp = (h0 > 0.f ? h0 : 0.f) * w2v[0] + (h1 > 0.f ? h1 : 0.f) * w2v[1];
            pp += __shfl_xor(pp, 1);  pp += __shfl_xor(pp, 2);
            pp += __shfl_xor(pp, 4);  pp += __shfl_xor(pp, 8);
            pp += __shfl_xor(pp, 16);
            if (l31 == 0)
                red[wv][mt * 32 + (r & 3) + 8 * (r >> 2) + 4 * q8] = pp;
        }
    }
    __syncthreads();

    if (tid < TE) {
        int eg = base + tid;
        if (eg < E) {
            float raw = red[0][tid] + red[1][tid] + red[2][tid] + red[3][tid] + b2s;
            out[eg] = (raw < T_SM) ? 0.f : raw;
            if (fabsf(raw - T_SM) < MARGIN_FB) {
                int pos = atomicAdd(count, 1);
                if (pos < cap) list[pos] = eg;
            }
        }
    }
}

// ---- exact fp32 recompute of near-threshold edges (one wave/edge) ----
__global__ __launch_bounds__(256, 4)
void fixup_kernel(const float* __restrict__ emb, const int* __restrict__ ei,
                  const float* __restrict__ W1, const float* __restrict__ b1,
                  const float* __restrict__ W2, const float* __restrict__ b2p,
                  const int* __restrict__ count, const int* __restrict__ list,
                  float* __restrict__ out, int E, int cap)
{
    int cnt = *count; if (cnt > cap) cnt = cap;
    const int lane = threadIdx.x & 63;
    const int gw = (blockIdx.x * 256 + threadIdx.x) >> 6;
    const int nw = (gridDim.x * 256) >> 6;
    for (int i = gw; i < cnt; i += nw) {
        int e = list[i];
        int rn = ei[e], cn = ei[E + e];
        const float* src = (lane < 32) ? emb + (size_t)rn * 128 + lane * 4
                                       : emb + (size_t)cn * 128 + (lane - 32) * 4;
        float4 xv = *(const float4*)src;
        float hacc[4] = {0.f, 0.f, 0.f, 0.f};
        for (int k0 = 0; k0 < 256; k0 += 4) {
            int sl = k0 >> 2;
            float x0 = __shfl(xv.x, sl), x1 = __shfl(xv.y, sl);
            float x2 = __shfl(xv.z, sl), x3 = __shfl(xv.w, sl);
            #pragma unroll
            for (int c = 0; c < 4; ++c) {
                int col = lane + 64 * c;
                hacc[c] += x0 * W1[(k0 + 0) * 256 + col] + x1 * W1[(k0 + 1) * 256 + col]
                         + x2 * W1[(k0 + 2) * 256 + col] + x3 * W1[(k0 + 3) * 256 + col];
            }
        }
        float p = 0.f;
        #pragma unroll
        for (int c = 0; c < 4; ++c) {
            float h = hacc[c] + b1[lane + 64 * c];
            p += (h > 0.f ? h : 0.f) * W2[lane + 64 * c];
        }
        p += __shfl_xor(p, 1);  p += __shfl_xor(p, 2);  p += __shfl_xor(p, 4);
        p += __shfl_xor(p, 8);  p += __shfl_xor(p, 16); p += __shfl_xor(p, 32);
        if (lane == 0) {
            float raw = p + b2p[0];
            out[e] = (raw < T_SM) ? 0.f : raw;
        }
    }
}

extern "C" void kernel_launch(void* const* d_in, const int* in_sizes, int n_in,
                              void* d_out, int out_size, void* d_ws, size_t ws_size,
                              hipStream_t stream) {
    const float* emb = (const float*)d_in[0];
    const int*   ei  = (const int*)  d_in[1];
    const float* W1  = (const float*)d_in[2];
    const float* b1  = (const float*)d_in[3];
    const float* W2  = (const float*)d_in[4];
    const float* b2  = (const float*)d_in[5];
    float* out = (float*)d_out;
    const int E  = out_size;
    const int Nn = in_sizes[0] / 128;

    const size_t yBytes = (size_t)Nn * 512 * sizeof(_Float16);   // 102.4 MB @ N=100000
    const size_t fastNeed = yBytes + 262144 + 64 + 65536;

    if (ws_size >= fastNeed) {
        // fast path: factorized Y-table
        _Float16* Y = (_Float16*)d_ws;
        u16* w1tT  = (u16*)((char*)d_ws + yBytes);
        int* count = (int*)((char*)d_ws + yBytes + 262144);
        int* list  = (int*)((char*)d_ws + yBytes + 262208);
        int cap = (int)((ws_size - (yBytes + 262208)) / 4);
        if (cap > E) cap = E;

        hipLaunchKernelGGL(prep_kernelT, dim3(256), dim3(256), 0, stream, W1, w1tT, count);
        hipLaunchKernelGGL(gemm_y_kernel, dim3((Nn + TE - 1) / TE), dim3(THREADS), 0, stream,
                           emb, w1tT, Y, Nn);
        hipLaunchKernelGGL(edge_kernel, dim3(4096), dim3(256), 0, stream,
                           Y, ei, b1, W2, b2, out, count, list, cap, E);
        hipLaunchKernelGGL(fixup_kernel, dim3(1024), dim3(256), 0, stream,
                           emb, ei, W1, b1, W2, b2, count, list, out, E, cap);
    } else {
        // fallback: R5 fused edge-GEMM (proven)
        u16* w1t   = (u16*)d_ws;
        int* count = (int*)((char*)d_ws + 262144);
        int* list  = (int*)((char*)d_ws + 262208);
        long avail = (long)ws_size - 262208;
        int cap = (avail > 4) ? (int)(avail / 4) : 0;
        if (cap > E) cap = E;

        hipLaunchKernelGGL(prep_kernel, dim3(256), dim3(256), 0, stream, W1, w1t, count);
        hipLaunchKernelGGL(linkmlp_mfma, dim3((E + TE - 1) / TE), dim3(THREADS), 0, stream,
                           emb, ei, w1t, b1, W2, b2, out, count, list, cap, E);
        hipLaunchKernelGGL(fixup_kernel, dim3(128), dim3(256), 0, stream,
                           emb, ei, W1, b1, W2, b2, count, list, out, E, cap);
    }
}

// Round 10
// 384.649 us; speedup vs baseline: 1.1311x; 1.0803x over previous
//
#include <hip/hip_runtime.h>

#define TE 64
#define THREADS 256
#define XS 136         // u16 LDS stride per row: 128 + 8 pad (conflict-free)
#define T_SM 0.05f
#define MARGIN_FAST 1e-2f   // covers fp16-Y raw-err tail (observed absmax 0.0078)
#define MARGIN_FB   1e-3f

typedef short s8v __attribute__((ext_vector_type(8)));    // 8 bf16 = 4 VGPRs (MFMA A/B frag)
typedef float f16v __attribute__((ext_vector_type(16)));  // 32x32 C/D frag
typedef unsigned short u16;

__device__ __forceinline__ u16 f2bf(float x) {            // fp32 -> bf16 RNE
    union { float f; unsigned u; } v; v.f = x;
    return (u16)((v.u + 0x7FFFu + ((v.u >> 16) & 1u)) >> 16);
}
__device__ __forceinline__ float bf2f(u16 h) {
    union { unsigned u; float f; } v; v.u = ((unsigned)h) << 16;
    return v.f;
}

// ---- fast-path prep: W1 [256,256] f32 -> TRANSPOSED fragment planes ----
// hi plane: w1tT[g*2048 + n*8 + j], lo plane at +65536 (u16 units); g=k>>3, j=k&7.
__global__ void prep_kernelT(const float* __restrict__ W1, u16* __restrict__ w1tT,
                             int* __restrict__ count) {
    int t = blockIdx.x * 256 + threadIdx.x;
    if (t == 0) *count = 0;
    if (t < 65536) {
        int n = t & 255, k = t >> 8;
        float w = W1[k * 256 + n];
        u16 h = f2bf(w);
        u16 l = f2bf(w - bf2f(h));
        int g = k >> 3, j = k & 7;
        w1tT[g * 2048 + n * 8 + j] = h;
        w1tT[65536 + g * 2048 + n * 8 + j] = l;
    }
}

// ---- fallback prep: per-n fragment layout (fallback kernel only) ----
__global__ void prep_kernel(const float* __restrict__ W1, u16* __restrict__ w1t,
                            int* __restrict__ count) {
    int t = blockIdx.x * 256 + threadIdx.x;
    if (t == 0) *count = 0;
    if (t < 65536) {
        int n = t & 255, k = t >> 8;
        float w = W1[k * 256 + n];
        u16 h = f2bf(w);
        u16 l = f2bf(w - bf2f(h));
        int g = k >> 3, j = k & 7;
        w1t[n * 512 + g * 16 + j] = h;
        w1t[n * 512 + g * 16 + j + 8] = l;
    }
}

// ============================ FAST PATH ============================
// Dense GEMM: Y[n][0:256]=emb[n]@W1[0:128,:], Y[n][256:512]=emb[n]@W1[128:,:].
// R9-proven (absmax 0.0078). LDS union sized for the LARGER epilogue view (R8 lesson).
__global__ __launch_bounds__(THREADS, 2)
void gemm_y_kernel(const float* __restrict__ emb, const u16* __restrict__ w1tT,
                   _Float16* __restrict__ Y, int Nn)
{
    __shared__ u16 smem[TE * 520];           // 66560 B union: x staging | epilogue
    u16* x_hi = smem;                        // x view: [0, 2*TE*XS) = 34816 B
    u16* x_lo = smem + TE * XS;
    u16* ep   = smem;                        // epilogue view: 64 nodes x 520 u16

    const int tid  = threadIdx.x;
    const int base = blockIdx.x * TE;
    const int lane = tid & 63;
    const int wv   = tid >> 6;
    const int l31  = lane & 31;
    const int q8   = lane >> 5;
    const int ge   = tid >> 5;
    const int gseg = tid & 31;

    #pragma unroll
    for (int q = 0; q < 8; ++q) {
        int node = base + ge + 8 * q;
        if (node >= Nn) node = Nn - 1;
        float4 v = ((const float4*)(emb + (size_t)node * 128))[gseg];
        u16 h0 = f2bf(v.x), h1 = f2bf(v.y), h2 = f2bf(v.z), h3 = f2bf(v.w);
        u16 l0 = f2bf(v.x - bf2f(h0)), l1 = f2bf(v.y - bf2f(h1));
        u16 l2 = f2bf(v.z - bf2f(h2)), l3 = f2bf(v.w - bf2f(h3));
        int off = (ge + 8 * q) * XS + gseg * 4;
        *(uint2*)&x_hi[off] = make_uint2((unsigned)h0 | ((unsigned)h1 << 16),
                                         (unsigned)h2 | ((unsigned)h3 << 16));
        *(uint2*)&x_lo[off] = make_uint2((unsigned)l0 | ((unsigned)l1 << 16),
                                         (unsigned)l2 | ((unsigned)l3 << 16));
    }
    __syncthreads();

    f16v acc[2][4];
    #pragma unroll
    for (int mt = 0; mt < 2; ++mt)
        #pragma unroll
        for (int nt = 0; nt < 4; ++nt)
            acc[mt][nt] = (f16v)0.f;

    const int arow0 = l31 * XS;
    const int arow1 = (32 + l31) * XS;
    int noff[4];
    #pragma unroll
    for (int nt = 0; nt < 4; ++nt)
        noff[nt] = ((wv * 128 + nt * 32 + l31) & 255) * 8;
    const int gbase = (wv >> 1) * 16;              // wv 0,1 -> Yr; wv 2,3 -> Yc

    #pragma unroll
    for (int sl = 0; sl < 8; ++sl) {
        const int aoff = 16 * sl + 8 * q8;
        s8v ah0 = *(const s8v*)&x_hi[arow0 + aoff];
        s8v ah1 = *(const s8v*)&x_hi[arow1 + aoff];
        s8v al0 = *(const s8v*)&x_lo[arow0 + aoff];
        s8v al1 = *(const s8v*)&x_lo[arow1 + aoff];
        const u16* gb = w1tT + (gbase + 2 * sl + q8) * 2048;
        #pragma unroll
        for (int nt = 0; nt < 4; ++nt) {
            s8v bh = *(const s8v*)(gb + noff[nt]);          // coalesced 512B/half-wave
            s8v bl = *(const s8v*)(gb + 65536 + noff[nt]);
            acc[0][nt] = __builtin_amdgcn_mfma_f32_32x32x16_bf16(ah0, bh, acc[0][nt], 0, 0, 0);
            acc[0][nt] = __builtin_amdgcn_mfma_f32_32x32x16_bf16(ah0, bl, acc[0][nt], 0, 0, 0);
            acc[0][nt] = __builtin_amdgcn_mfma_f32_32x32x16_bf16(al0, bh, acc[0][nt], 0, 0, 0);
            acc[1][nt] = __builtin_amdgcn_mfma_f32_32x32x16_bf16(ah1, bh, acc[1][nt], 0, 0, 0);
            acc[1][nt] = __builtin_amdgcn_mfma_f32_32x32x16_bf16(ah1, bl, acc[1][nt], 0, 0, 0);
            acc[1][nt] = __builtin_amdgcn_mfma_f32_32x32x16_bf16(al1, bh, acc[1][nt], 0, 0, 0);
        }
    }

    __syncthreads();                               // all x reads done; smem reused
    #pragma unroll
    for (int mt = 0; mt < 2; ++mt) {
        #pragma unroll
        for (int nt = 0; nt < 4; ++nt) {
            int c = wv * 128 + nt * 32 + l31;
            #pragma unroll
            for (int r = 0; r < 16; ++r) {
                int node64 = mt * 32 + (r & 3) + 8 * (r >> 2) + 4 * q8;
                ep[node64 * 520 + c] = (u16)__builtin_bit_cast(unsigned short, (_Float16)acc[mt][nt][r]);
            }
        }
    }
    __syncthreads();

    #pragma unroll
    for (int i = 0; i < 16; ++i) {
        int ch = tid + 256 * i;
        int node64 = ch >> 6;
        int cg = ch & 63;
        int gnode = base + node64;
        if (gnode < Nn) {
            uint4 v = *(const uint4*)&ep[node64 * 520 + 8 * cg];
            *(uint4*)(Y + (size_t)gnode * 512 + 8 * cg) = v;
        }
    }
}

// ---- warm kernel: sequential read of Y to pull it L2/L3-resident before edge pass ----
// Theory: R6's scattered-2B Y stores (RMW, write-allocate) left Y cached -> edge 107us;
// R7/R9's full-line streaming stores did not -> edge 169us. This reproduces the warmth.
__global__ __launch_bounds__(256, 8)
void warm_kernel(const uint4* __restrict__ Y, unsigned n16, unsigned* __restrict__ sink) {
    unsigned i = blockIdx.x * 256 + threadIdx.x;
    const unsigned stride = gridDim.x * 256;
    unsigned acc = 0;
    for (; i < n16; i += stride) {
        uint4 v = Y[i];
        acc ^= v.x ^ v.y ^ v.z ^ v.w;
    }
    if (acc == 0xDEADBEEFu) *sink = acc;   // keep the loads alive; write is ~never taken
}

// Edge pass (R6-proven config): raw(e) = relu(Yr[row]+Yc[col]+b1) . W2 + b2.
__global__ __launch_bounds__(256, 6)
void edge_kernel(const _Float16* __restrict__ Y, const int* __restrict__ ei,
                 const float* __restrict__ b1, const float* __restrict__ W2,
                 const float* __restrict__ b2p, float* __restrict__ out,
                 int* __restrict__ count, int* __restrict__ list, int cap, int E)
{
    const int tid = threadIdx.x;
    const int l31 = tid & 31;
    const int q8  = (tid & 63) >> 5;
    const int gw  = (blockIdx.x * 256 + tid) >> 6;
    const int nw  = (gridDim.x * 256) >> 6;

    float b1v[8], w2v[8];
    #pragma unroll
    for (int j = 0; j < 8; ++j) {
        b1v[j] = b1[8 * l31 + j];
        w2v[j] = W2[8 * l31 + j];
    }
    const float b2s = b2p[0];
    const int npairs = (E + 1) >> 1;

    for (int pair = gw; pair < npairs; pair += nw) {
        int e = 2 * pair + q8;
        bool valid = e < E;
        int es = valid ? e : 0;
        int row = ei[es], col = ei[E + es];
        union { uint4 u; _Float16 h[8]; } yr, yc;
        yr.u = *(const uint4*)(Y + (size_t)row * 512 + 8 * l31);
        yc.u = *(const uint4*)(Y + (size_t)col * 512 + 256 + 8 * l31);
        float p = 0.f;
        #pragma unroll
        for (int j = 0; j < 8; ++j) {
            float h = (float)yr.h[j] + (float)yc.h[j] + b1v[j];
            p += (h > 0.f ? h : 0.f) * w2v[j];
        }
        p += __shfl_xor(p, 1);  p += __shfl_xor(p, 2);  p += __shfl_xor(p, 4);
        p += __shfl_xor(p, 8);  p += __shfl_xor(p, 16);
        if (l31 == 0 && valid) {
            float raw = p + b2s;
            out[e] = (raw < T_SM) ? 0.f : raw;
            if (fabsf(raw - T_SM) < MARGIN_FAST) {
                int pos = atomicAdd(count, 1);
                if (pos < cap) list[pos] = e;
            }
        }
    }
}

// ---- batched exact fp32 fixup: 64 listed edges per tile (R2-proven structure) ----
// Replaces wave-per-edge fixup (which re-read 256KB W1 per edge -> ~3.3GB L2 for 13k
// edges). Here W1 streams once per 64-edge tile: 205 tiles -> ~51MB.
__global__ __launch_bounds__(256, 3)
void fixup_tile_kernel(const float* __restrict__ emb, const int* __restrict__ ei,
                       const float* __restrict__ W1, const float* __restrict__ b1,
                       const float* __restrict__ W2, const float* __restrict__ b2p,
                       const int* __restrict__ count, const int* __restrict__ list,
                       float* __restrict__ out, int E, int cap)
{
    __shared__ float x_lds[TE * 132];
    __shared__ float red[4][TE];
    __shared__ int s_e[TE];
    __shared__ int s_idx[2][TE];

    int cnt = *count; if (cnt > cap) cnt = cap;
    const int ntiles = (cnt + TE - 1) / TE;
    const int tid = threadIdx.x;
    const int je = tid & 7, jc = tid >> 3, c0 = jc * 8;
    const int lane = tid & 63, wv = tid >> 6;

    for (int t = blockIdx.x; t < ntiles; t += gridDim.x) {
        const int tb = t * TE;
        if (tid < TE) {
            int i = tb + tid;
            int e = (i < cnt) ? list[i] : list[0];
            s_e[tid] = (i < cnt) ? e : -1;
            s_idx[0][tid] = ei[e];
            s_idx[1][tid] = ei[E + e];
        }
        __syncthreads();

        float acc[8][8];
        #pragma unroll
        for (int i = 0; i < 8; ++i)
            #pragma unroll
            for (int j = 0; j < 8; ++j)
                acc[i][j] = 0.f;

        for (int half = 0; half < 2; ++half) {
            const int* nodes = s_idx[half];
            #pragma unroll
            for (int q = 0; q < 8; ++q) {
                int f = tid + THREADS * q;
                int e2 = f >> 5, seg = f & 31;
                *(float4*)(&x_lds[e2 * 132 + seg * 4]) =
                    ((const float4*)(emb + (size_t)nodes[e2] * 128))[seg];
            }
            __syncthreads();

            const float* Wb = W1 + (half * 128) * 256;
            for (int k0 = 0; k0 < 128; k0 += 4) {
                float4 wrow[4][2];
                #pragma unroll
                for (int r = 0; r < 4; ++r) {
                    const float* wr = Wb + (k0 + r) * 256 + c0;
                    wrow[r][0] = *(const float4*)(wr);
                    wrow[r][1] = *(const float4*)(wr + 4);
                }
                #pragma unroll
                for (int i = 0; i < 8; ++i) {
                    float4 xv = *(const float4*)(&x_lds[(je + 8 * i) * 132 + k0]);
                    const float xk[4] = {xv.x, xv.y, xv.z, xv.w};
                    #pragma unroll
                    for (int r = 0; r < 4; ++r) {
                        const float4 wa = wrow[r][0];
                        const float4 wb = wrow[r][1];
                        acc[i][0] += xk[r] * wa.x;  acc[i][1] += xk[r] * wa.y;
                        acc[i][2] += xk[r] * wa.z;  acc[i][3] += xk[r] * wa.w;
                        acc[i][4] += xk[r] * wb.x;  acc[i][5] += xk[r] * wb.y;
                        acc[i][6] += xk[r] * wb.z;  acc[i][7] += xk[r] * wb.w;
                    }
                }
            }
            __syncthreads();
        }

        float b1v[8], w2v[8];
        #pragma unroll
        for (int j = 0; j < 8; ++j) {
            b1v[j] = b1[c0 + j];
            w2v[j] = W2[c0 + j];
        }
        #pragma unroll
        for (int i = 0; i < 8; ++i) {
            float p = 0.f;
            #pragma unroll
            for (int j = 0; j < 8; ++j) {
                float h = acc[i][j] + b1v[j];
                p += (h > 0.f ? h : 0.f) * w2v[j];
            }
            p += __shfl_xor(p, 8);
            p += __shfl_xor(p, 16);
            p += __shfl_xor(p, 32);
            if ((lane >> 3) == 0)
                red[wv][je + 8 * i] = p;
        }
        __syncthreads();

        if (tid < TE && s_e[tid] >= 0) {
            float raw = red[0][tid] + red[1][tid] + red[2][tid] + red[3][tid] + b2p[0];
            out[s_e[tid]] = (raw < T_SM) ? 0.f : raw;
        }
        __syncthreads();
    }
}

// ============================ FALLBACK PATH (R5, proven) ============================
__global__ __launch_bounds__(THREADS, 3)
void linkmlp_mfma(const float* __restrict__ emb, const int* __restrict__ ei,
                  const u16* __restrict__ w1t, const float* __restrict__ b1,
                  const float* __restrict__ W2, const float* __restrict__ b2p,
                  float* __restrict__ out, int* __restrict__ count,
                  int* __restrict__ list, int cap, int E)
{
    __shared__ u16 x_hi[TE * XS];
    __shared__ u16 x_lo[TE * XS];
    __shared__ float red[4][TE];
    __shared__ int s_idx[2][TE];

    const int tid  = threadIdx.x;
    const int base = blockIdx.x * TE;
    const int lane = tid & 63;
    const int wv   = tid >> 6;
    const int l31  = lane & 31;
    const int q8   = lane >> 5;
    const int ge   = tid >> 5;
    const int gseg = tid & 31;

    if (tid < TE) { int e = base + tid; s_idx[0][tid] = (e < E) ? ei[e] : 0; }
    else if (tid < 2 * TE) { int t2 = tid - TE; int e = base + t2; s_idx[1][t2] = (e < E) ? ei[E + e] : 0; }
    __syncthreads();

    float b1v[2], w2v[2];
    #pragma unroll
    for (int nt = 0; nt < 2; ++nt) {
        int c = wv * 64 + nt * 32 + l31;
        b1v[nt] = b1[c];
        w2v[nt] = W2[c];
    }
    const float b2s = b2p[0];

    f16v acc[2][2];
    #pragma unroll
    for (int mt = 0; mt < 2; ++mt)
        #pragma unroll
        for (int nt = 0; nt < 2; ++nt)
            acc[mt][nt] = (f16v)0.f;

    float4 gv[8];
    auto issue_gather = [&](int half) {
        #pragma unroll
        for (int q = 0; q < 8; ++q) {
            int node = s_idx[half][ge + 8 * q];
            gv[q] = ((const float4*)(emb + (size_t)node * 128))[gseg];
        }
    };
    auto write_gather = [&]() {
        #pragma unroll
        for (int q = 0; q < 8; ++q) {
            float4 v = gv[q];
            u16 h0 = f2bf(v.x), h1 = f2bf(v.y), h2 = f2bf(v.z), h3 = f2bf(v.w);
            u16 l0 = f2bf(v.x - bf2f(h0)), l1 = f2bf(v.y - bf2f(h1));
            u16 l2 = f2bf(v.z - bf2f(h2)), l3 = f2bf(v.w - bf2f(h3));
            int off = (ge + 8 * q) * XS + gseg * 4;
            *(uint2*)&x_hi[off] = make_uint2((unsigned)h0 | ((unsigned)h1 << 16),
                                             (unsigned)h2 | ((unsigned)h3 << 16));
            *(uint2*)&x_lo[off] = make_uint2((unsigned)l0 | ((unsigned)l1 << 16),
                                             (unsigned)l2 | ((unsigned)l3 << 16));
        }
    };

    issue_gather(0);
    write_gather();
    __syncthreads();

    #pragma unroll
    for (int half = 0; half < 2; ++half) {
        const int arow0 = l31 * XS;
        const int arow1 = (32 + l31) * XS;
        const u16* bbase0 = w1t + (size_t)(wv * 64 + l31) * 512 + (half * 16 + q8) * 16;
        const u16* bbase1 = bbase0 + 32 * 512;
        if (half == 0) issue_gather(1);

        auto kstep = [&](int sl) {
            const int aoff = 16 * sl + 8 * q8;
            s8v ah0 = *(const s8v*)&x_hi[arow0 + aoff];
            s8v ah1 = *(const s8v*)&x_hi[arow1 + aoff];
            s8v al0 = *(const s8v*)&x_lo[arow0 + aoff];
            s8v al1 = *(const s8v*)&x_lo[arow1 + aoff];
            const u16* bp0 = bbase0 + sl * 32;
            const u16* bp1 = bbase1 + sl * 32;
            s8v bh0 = *(const s8v*)bp0;  s8v bl0 = *(const s8v*)(bp0 + 8);
            s8v bh1 = *(const s8v*)bp1;  s8v bl1 = *(const s8v*)(bp1 + 8);
            acc[0][0] = __builtin_amdgcn_mfma_f32_32x32x16_bf16(ah0, bh0, acc[0][0], 0, 0, 0);
            acc[0][0] = __builtin_amdgcn_mfma_f32_32x32x16_bf16(ah0, bl0, acc[0][0], 0, 0, 0);
            acc[0][0] = __builtin_amdgcn_mfma_f32_32x32x16_bf16(al0, bh0, acc[0][0], 0, 0, 0);
            acc[1][0] = __builtin_amdgcn_mfma_f32_32x32x16_bf16(ah1, bh0, acc[1][0], 0, 0, 0);
            acc[1][0] = __builtin_amdgcn_mfma_f32_32x32x16_bf16(ah1, bl0, acc[1][0], 0, 0, 0);
            acc[1][0] = __builtin_amdgcn_mfma_f32_32x32x16_bf16(al1, bh0, acc[1][0], 0, 0, 0);
            acc[0][1] = __builtin_amdgcn_mfma_f32_32x32x16_bf16(ah0, bh1, acc[0][1], 0, 0, 0);
            acc[0][1] = __builtin_amdgcn_mfma_f32_32x32x16_bf16(ah0, bl1, acc[0][1], 0, 0, 0);
            acc[0][1] = __builtin_amdgcn_mfma_f32_32x32x16_bf16(al0, bh1, acc[0][1], 0, 0, 0);
            acc[1][1] = __builtin_amdgcn_mfma_f32_32x32x16_bf16(ah1, bh1, acc[1][1], 0, 0, 0);
            acc[1][1] = __builtin_amdgcn_mfma_f32_32x32x16_bf16(ah1, bl1, acc[1][1], 0, 0, 0);
            acc[1][1] = __builtin_amdgcn_mfma_f32_32x32x16_bf16(al1, bh1, acc[1][1], 0, 0, 0);
        };

        kstep(0); kstep(1); kstep(2); kstep(3);
        kstep(4); kstep(5); kstep(6); kstep(7);

        if (half == 0) {
            __syncthreads();
            write_gather();
            __syncthreads();
        }
    }

    #pragma unroll
    for (int mt = 0; mt < 2; ++mt) {
        #pragma unroll
        for (int r = 0; r < 16; ++r) {
            float h0 = acc[mt][0][r] + b1v[0];
            float h1 = acc[mt][1][r] + b1v[1];
            float pp = (h0 > 0.f ? h0 : 0.f) * w2v[0] + (h1 > 0.f ? h1 : 0.f) * w2v[1];
            pp += __shfl_xor(pp, 1);  pp += __shfl_xor(pp, 2);
            pp += __shfl_xor(pp, 4);  pp += __shfl_xor(pp, 8);
            pp += __shfl_xor(pp, 16);
            if (l31 == 0)
                red[wv][mt * 32 + (r & 3) + 8 * (r >> 2) + 4 * q8] = pp;
        }
    }
    __syncthreads();

    if (tid < TE) {
        int eg = base + tid;
        if (eg < E) {
            float raw = red[0][tid] + red[1][tid] + red[2][tid] + red[3][tid] + b2s;
            out[eg] = (raw < T_SM) ? 0.f : raw;
            if (fabsf(raw - T_SM) < MARGIN_FB) {
                int pos = atomicAdd(count, 1);
                if (pos < cap) list[pos] = eg;
            }
        }
    }
}

extern "C" void kernel_launch(void* const* d_in, const int* in_sizes, int n_in,
                              void* d_out, int out_size, void* d_ws, size_t ws_size,
                              hipStream_t stream) {
    const float* emb = (const float*)d_in[0];
    const int*   ei  = (const int*)  d_in[1];
    const float* W1  = (const float*)d_in[2];
    const float* b1  = (const float*)d_in[3];
    const float* W2  = (const float*)d_in[4];
    const float* b2  = (const float*)d_in[5];
    float* out = (float*)d_out;
    const int E  = out_size;
    const int Nn = in_sizes[0] / 128;

    const size_t yBytes = (size_t)Nn * 512 * sizeof(_Float16);   // 102.4 MB @ N=100000
    const size_t fastNeed = yBytes + 262144 + 64 + 65536;

    if (ws_size >= fastNeed) {
        // fast path: factorized Y-table
        _Float16* Y = (_Float16*)d_ws;
        u16* w1tT  = (u16*)((char*)d_ws + yBytes);
        int* count = (int*)((char*)d_ws + yBytes + 262144);
        unsigned* sink = (unsigned*)((char*)d_ws + yBytes + 262144 + 16);
        int* list  = (int*)((char*)d_ws + yBytes + 262208);
        int cap = (int)((ws_size - (yBytes + 262208)) / 4);
        if (cap > E) cap = E;
        const unsigned n16 = (unsigned)((size_t)Nn * 512 * 2 / 16);

        hipLaunchKernelGGL(prep_kernelT, dim3(256), dim3(256), 0, stream, W1, w1tT, count);
        hipLaunchKernelGGL(gemm_y_kernel, dim3((Nn + TE - 1) / TE), dim3(THREADS), 0, stream,
                           emb, w1tT, Y, Nn);
        hipLaunchKernelGGL(warm_kernel, dim3(1024), dim3(256), 0, stream,
                           (const uint4*)Y, n16, sink);
        hipLaunchKernelGGL(edge_kernel, dim3(4096), dim3(256), 0, stream,
                           Y, ei, b1, W2, b2, out, count, list, cap, E);
        hipLaunchKernelGGL(fixup_tile_kernel, dim3(256), dim3(256), 0, stream,
                           emb, ei, W1, b1, W2, b2, count, list, out, E, cap);
    } else {
        // fallback: R5 fused edge-GEMM (proven)
        u16* w1t   = (u16*)d_ws;
        int* count = (int*)((char*)d_ws + 262144);
        int* list  = (int*)((char*)d_ws + 262208);
        long avail = (long)ws_size - 262208;
        int cap = (avail > 4) ? (int)(avail / 4) : 0;
        if (cap > E) cap = E;

        hipLaunchKernelGGL(prep_kernel, dim3(256), dim3(256), 0, stream, W1, w1t, count);
        hipLaunchKernelGGL(linkmlp_mfma, dim3((E + TE - 1) / TE), dim3(THREADS), 0, stream,
                           emb, ei, w1t, b1, W2, b2, out, count, list, cap, E);
        hipLaunchKernelGGL(fixup_tile_kernel, dim3(256), dim3(256), 0, stream,
                           emb, ei, W1, b1, W2, b2, count, list, out, E, cap);
    }
}

// Round 11
// 370.217 us; speedup vs baseline: 1.1752x; 1.0390x over previous
//
#include <hip/hip_runtime.h>

#define TE 64
#define THREADS 256
#define XS 136         // u16 LDS stride per row: 128 + 8 pad (conflict-free)
#define T_SM 0.05f
#define MARGIN_FAST 1e-2f   // covers fp16-Y raw-err tail (observed absmax 0.0078)
#define MARGIN_FB   1e-3f

typedef short s8v __attribute__((ext_vector_type(8)));    // 8 bf16 = 4 VGPRs (MFMA A/B frag)
typedef float f16v __attribute__((ext_vector_type(16)));  // 32x32 C/D frag
typedef unsigned short u16;

__device__ __forceinline__ u16 f2bf(float x) {            // fp32 -> bf16 RNE
    union { float f; unsigned u; } v; v.f = x;
    return (u16)((v.u + 0x7FFFu + ((v.u >> 16) & 1u)) >> 16);
}
__device__ __forceinline__ float bf2f(u16 h) {
    union { unsigned u; float f; } v; v.u = ((unsigned)h) << 16;
    return v.f;
}

// ---- fast-path prep: W1 [256,256] f32 -> TRANSPOSED fragment planes ----
// hi plane: w1tT[g*2048 + n*8 + j], lo plane at +65536 (u16 units); g=k>>3, j=k&7.
__global__ void prep_kernelT(const float* __restrict__ W1, u16* __restrict__ w1tT,
                             int* __restrict__ count) {
    int t = blockIdx.x * 256 + threadIdx.x;
    if (t == 0) *count = 0;
    if (t < 65536) {
        int n = t & 255, k = t >> 8;
        float w = W1[k * 256 + n];
        u16 h = f2bf(w);
        u16 l = f2bf(w - bf2f(h));
        int g = k >> 3, j = k & 7;
        w1tT[g * 2048 + n * 8 + j] = h;
        w1tT[65536 + g * 2048 + n * 8 + j] = l;
    }
}

// ---- fallback prep: per-n fragment layout (fallback kernel only) ----
__global__ void prep_kernel(const float* __restrict__ W1, u16* __restrict__ w1t,
                            int* __restrict__ count) {
    int t = blockIdx.x * 256 + threadIdx.x;
    if (t == 0) *count = 0;
    if (t < 65536) {
        int n = t & 255, k = t >> 8;
        float w = W1[k * 256 + n];
        u16 h = f2bf(w);
        u16 l = f2bf(w - bf2f(h));
        int g = k >> 3, j = k & 7;
        w1t[n * 512 + g * 16 + j] = h;
        w1t[n * 512 + g * 16 + j + 8] = l;
    }
}

// ============================ FAST PATH ============================
// Dense GEMM: Y[n][0:256]=emb[n]@W1[0:128,:], Y[n][256:512]=emb[n]@W1[128:,:].
// Col mapping: lane owns 4 CONSECUTIVE cols c = wv*128 + l31*4 + nt (R7-style) so the
// epilogue is 32 packed 8B stores/thread (256B contiguous per half-wave) with NO LDS
// round-trip. B loads use the g-major w1tT (R9 layout): 64B lane stride, L2-resident,
// hidden under the 24-MFMA (768 cyc) shadow per kstep. Y values bit-identical to R9/R10.
__global__ __launch_bounds__(THREADS, 2)
void gemm_y_kernel(const float* __restrict__ emb, const u16* __restrict__ w1tT,
                   _Float16* __restrict__ Y, int Nn)
{
    __shared__ u16 x_hi[TE * XS];      // 34816 B total LDS (no epilogue view needed)
    __shared__ u16 x_lo[TE * XS];

    const int tid  = threadIdx.x;
    const int base = blockIdx.x * TE;
    const int lane = tid & 63;
    const int wv   = tid >> 6;
    const int l31  = lane & 31;
    const int q8   = lane >> 5;
    const int ge   = tid >> 5;
    const int gseg = tid & 31;

    // two-phase staging: issue all 8 gathers, then convert+write (max loads in flight)
    float4 gvf[8];
    #pragma unroll
    for (int q = 0; q < 8; ++q) {
        int node = base + ge + 8 * q;
        if (node >= Nn) node = Nn - 1;
        gvf[q] = ((const float4*)(emb + (size_t)node * 128))[gseg];
    }
    #pragma unroll
    for (int q = 0; q < 8; ++q) {
        float4 v = gvf[q];
        u16 h0 = f2bf(v.x), h1 = f2bf(v.y), h2 = f2bf(v.z), h3 = f2bf(v.w);
        u16 l0 = f2bf(v.x - bf2f(h0)), l1 = f2bf(v.y - bf2f(h1));
        u16 l2 = f2bf(v.z - bf2f(h2)), l3 = f2bf(v.w - bf2f(h3));
        int off = (ge + 8 * q) * XS + gseg * 4;
        *(uint2*)&x_hi[off] = make_uint2((unsigned)h0 | ((unsigned)h1 << 16),
                                         (unsigned)h2 | ((unsigned)h3 << 16));
        *(uint2*)&x_lo[off] = make_uint2((unsigned)l0 | ((unsigned)l1 << 16),
                                         (unsigned)l2 | ((unsigned)l3 << 16));
    }
    __syncthreads();

    f16v acc[2][4];
    #pragma unroll
    for (int mt = 0; mt < 2; ++mt)
        #pragma unroll
        for (int nt = 0; nt < 4; ++nt)
            acc[mt][nt] = (f16v)0.f;

    const int arow0 = l31 * XS;
    const int arow1 = (32 + l31) * XS;
    int noff[4];                                   // n-part of B addr: lane-consecutive cols
    #pragma unroll
    for (int nt = 0; nt < 4; ++nt)
        noff[nt] = (((wv & 1) * 128) + l31 * 4 + nt) * 8;
    const int gbase = (wv >> 1) * 16;              // wv 0,1 -> Yr (g0..15); wv 2,3 -> Yc

    #pragma unroll
    for (int sl = 0; sl < 8; ++sl) {               // K=128 in 8 ksteps of 16
        const int aoff = 16 * sl + 8 * q8;
        s8v ah0 = *(const s8v*)&x_hi[arow0 + aoff];
        s8v ah1 = *(const s8v*)&x_hi[arow1 + aoff];
        s8v al0 = *(const s8v*)&x_lo[arow0 + aoff];
        s8v al1 = *(const s8v*)&x_lo[arow1 + aoff];
        const u16* gb = w1tT + (gbase + 2 * sl + q8) * 2048;
        #pragma unroll
        for (int nt = 0; nt < 4; ++nt) {
            s8v bh = *(const s8v*)(gb + noff[nt]);          // L2-hot, 2KB span/half-wave
            s8v bl = *(const s8v*)(gb + 65536 + noff[nt]);
            acc[0][nt] = __builtin_amdgcn_mfma_f32_32x32x16_bf16(ah0, bh, acc[0][nt], 0, 0, 0);
            acc[0][nt] = __builtin_amdgcn_mfma_f32_32x32x16_bf16(ah0, bl, acc[0][nt], 0, 0, 0);
            acc[0][nt] = __builtin_amdgcn_mfma_f32_32x32x16_bf16(al0, bh, acc[0][nt], 0, 0, 0);
            acc[1][nt] = __builtin_amdgcn_mfma_f32_32x32x16_bf16(ah1, bh, acc[1][nt], 0, 0, 0);
            acc[1][nt] = __builtin_amdgcn_mfma_f32_32x32x16_bf16(ah1, bl, acc[1][nt], 0, 0, 0);
            acc[1][nt] = __builtin_amdgcn_mfma_f32_32x32x16_bf16(al1, bh, acc[1][nt], 0, 0, 0);
        }
    }

    // epilogue: pack 4 consecutive cols -> one 8B store; 256B contiguous per half-wave
    #pragma unroll
    for (int mt = 0; mt < 2; ++mt) {
        #pragma unroll
        for (int r = 0; r < 16; ++r) {
            int node = base + mt * 32 + (r & 3) + 8 * (r >> 2) + 4 * q8;
            if (node < Nn) {
                _Float16 pk[4] = {(_Float16)acc[mt][0][r], (_Float16)acc[mt][1][r],
                                  (_Float16)acc[mt][2][r], (_Float16)acc[mt][3][r]};
                *(uint2*)(Y + (size_t)node * 512 + wv * 128 + l31 * 4) = *(uint2*)pk;
            }
        }
    }
}

// Edge pass (proven config): raw(e) = relu(Yr[row]+Yc[col]+b1) . W2 + b2.
__global__ __launch_bounds__(256, 6)
void edge_kernel(const _Float16* __restrict__ Y, const int* __restrict__ ei,
                 const float* __restrict__ b1, const float* __restrict__ W2,
                 const float* __restrict__ b2p, float* __restrict__ out,
                 int* __restrict__ count, int* __restrict__ list, int cap, int E)
{
    const int tid = threadIdx.x;
    const int l31 = tid & 31;
    const int q8  = (tid & 63) >> 5;
    const int gw  = (blockIdx.x * 256 + tid) >> 6;
    const int nw  = (gridDim.x * 256) >> 6;

    float b1v[8], w2v[8];
    #pragma unroll
    for (int j = 0; j < 8; ++j) {
        b1v[j] = b1[8 * l31 + j];
        w2v[j] = W2[8 * l31 + j];
    }
    const float b2s = b2p[0];
    const int npairs = (E + 1) >> 1;

    for (int pair = gw; pair < npairs; pair += nw) {
        int e = 2 * pair + q8;
        bool valid = e < E;
        int es = valid ? e : 0;
        int row = ei[es], col = ei[E + es];
        union { uint4 u; _Float16 h[8]; } yr, yc;
        yr.u = *(const uint4*)(Y + (size_t)row * 512 + 8 * l31);
        yc.u = *(const uint4*)(Y + (size_t)col * 512 + 256 + 8 * l31);
        float p = 0.f;
        #pragma unroll
        for (int j = 0; j < 8; ++j) {
            float h = (float)yr.h[j] + (float)yc.h[j] + b1v[j];
            p += (h > 0.f ? h : 0.f) * w2v[j];
        }
        p += __shfl_xor(p, 1);  p += __shfl_xor(p, 2);  p += __shfl_xor(p, 4);
        p += __shfl_xor(p, 8);  p += __shfl_xor(p, 16);
        if (l31 == 0 && valid) {
            float raw = p + b2s;
            out[e] = (raw < T_SM) ? 0.f : raw;
            if (fabsf(raw - T_SM) < MARGIN_FAST) {
                int pos = atomicAdd(count, 1);
                if (pos < cap) list[pos] = e;
            }
        }
    }
}

// ---- batched exact fp32 fixup: 64 listed edges per tile (R10-proven) ----
__global__ __launch_bounds__(256, 3)
void fixup_tile_kernel(const float* __restrict__ emb, const int* __restrict__ ei,
                       const float* __restrict__ W1, const float* __restrict__ b1,
                       const float* __restrict__ W2, const float* __restrict__ b2p,
                       const int* __restrict__ count, const int* __restrict__ list,
                       float* __restrict__ out, int E, int cap)
{
    __shared__ float x_lds[TE * 132];
    __shared__ float red[4][TE];
    __shared__ int s_e[TE];
    __shared__ int s_idx[2][TE];

    int cnt = *count; if (cnt > cap) cnt = cap;
    const int ntiles = (cnt + TE - 1) / TE;
    const int tid = threadIdx.x;
    const int je = tid & 7, jc = tid >> 3, c0 = jc * 8;
    const int lane = tid & 63, wv = tid >> 6;

    for (int t = blockIdx.x; t < ntiles; t += gridDim.x) {
        const int tb = t * TE;
        if (tid < TE) {
            int i = tb + tid;
            int e = (i < cnt) ? list[i] : list[0];
            s_e[tid] = (i < cnt) ? e : -1;
            s_idx[0][tid] = ei[e];
            s_idx[1][tid] = ei[E + e];
        }
        __syncthreads();

        float acc[8][8];
        #pragma unroll
        for (int i = 0; i < 8; ++i)
            #pragma unroll
            for (int j = 0; j < 8; ++j)
                acc[i][j] = 0.f;

        for (int half = 0; half < 2; ++half) {
            const int* nodes = s_idx[half];
            #pragma unroll
            for (int q = 0; q < 8; ++q) {
                int f = tid + THREADS * q;
                int e2 = f >> 5, seg = f & 31;
                *(float4*)(&x_lds[e2 * 132 + seg * 4]) =
                    ((const float4*)(emb + (size_t)nodes[e2] * 128))[seg];
            }
            __syncthreads();

            const float* Wb = W1 + (half * 128) * 256;
            for (int k0 = 0; k0 < 128; k0 += 4) {
                float4 wrow[4][2];
                #pragma unroll
                for (int r = 0; r < 4; ++r) {
                    const float* wr = Wb + (k0 + r) * 256 + c0;
                    wrow[r][0] = *(const float4*)(wr);
                    wrow[r][1] = *(const float4*)(wr + 4);
                }
                #pragma unroll
                for (int i = 0; i < 8; ++i) {
                    float4 xv = *(const float4*)(&x_lds[(je + 8 * i) * 132 + k0]);
                    const float xk[4] = {xv.x, xv.y, xv.z, xv.w};
                    #pragma unroll
                    for (int r = 0; r < 4; ++r) {
                        const float4 wa = wrow[r][0];
                        const float4 wb = wrow[r][1];
                        acc[i][0] += xk[r] * wa.x;  acc[i][1] += xk[r] * wa.y;
                        acc[i][2] += xk[r] * wa.z;  acc[i][3] += xk[r] * wa.w;
                        acc[i][4] += xk[r] * wb.x;  acc[i][5] += xk[r] * wb.y;
                        acc[i][6] += xk[r] * wb.z;  acc[i][7] += xk[r] * wb.w;
                    }
                }
            }
            __syncthreads();
        }

        float b1v[8], w2v[8];
        #pragma unroll
        for (int j = 0; j < 8; ++j) {
            b1v[j] = b1[c0 + j];
            w2v[j] = W2[c0 + j];
        }
        #pragma unroll
        for (int i = 0; i < 8; ++i) {
            float p = 0.f;
            #pragma unroll
            for (int j = 0; j < 8; ++j) {
                float h = acc[i][j] + b1v[j];
                p += (h > 0.f ? h : 0.f) * w2v[j];
            }
            p += __shfl_xor(p, 8);
            p += __shfl_xor(p, 16);
            p += __shfl_xor(p, 32);
            if ((lane >> 3) == 0)
                red[wv][je + 8 * i] = p;
        }
        __syncthreads();

        if (tid < TE && s_e[tid] >= 0) {
            float raw = red[0][tid] + red[1][tid] + red[2][tid] + red[3][tid] + b2p[0];
            out[s_e[tid]] = (raw < T_SM) ? 0.f : raw;
        }
        __syncthreads();
    }
}

// ============================ FALLBACK PATH (R5, proven) ============================
__global__ __launch_bounds__(THREADS, 3)
void linkmlp_mfma(const float* __restrict__ emb, const int* __restrict__ ei,
                  const u16* __restrict__ w1t, const float* __restrict__ b1,
                  const float* __restrict__ W2, const float* __restrict__ b2p,
                  float* __restrict__ out, int* __restrict__ count,
                  int* __restrict__ list, int cap, int E)
{
    __shared__ u16 x_hi[TE * XS];
    __shared__ u16 x_lo[TE * XS];
    __shared__ float red[4][TE];
    __shared__ int s_idx[2][TE];

    const int tid  = threadIdx.x;
    const int base = blockIdx.x * TE;
    const int lane = tid & 63;
    const int wv   = tid >> 6;
    const int l31  = lane & 31;
    const int q8   = lane >> 5;
    const int ge   = tid >> 5;
    const int gseg = tid & 31;

    if (tid < TE) { int e = base + tid; s_idx[0][tid] = (e < E) ? ei[e] : 0; }
    else if (tid < 2 * TE) { int t2 = tid - TE; int e = base + t2; s_idx[1][t2] = (e < E) ? ei[E + e] : 0; }
    __syncthreads();

    float b1v[2], w2v[2];
    #pragma unroll
    for (int nt = 0; nt < 2; ++nt) {
        int c = wv * 64 + nt * 32 + l31;
        b1v[nt] = b1[c];
        w2v[nt] = W2[c];
    }
    const float b2s = b2p[0];

    f16v acc[2][2];
    #pragma unroll
    for (int mt = 0; mt < 2; ++mt)
        #pragma unroll
        for (int nt = 0; nt < 2; ++nt)
            acc[mt][nt] = (f16v)0.f;

    float4 gv[8];
    auto issue_gather = [&](int half) {
        #pragma unroll
        for (int q = 0; q < 8; ++q) {
            int node = s_idx[half][ge + 8 * q];
            gv[q] = ((const float4*)(emb + (size_t)node * 128))[gseg];
        }
    };
    auto write_gather = [&]() {
        #pragma unroll
        for (int q = 0; q < 8; ++q) {
            float4 v = gv[q];
            u16 h0 = f2bf(v.x), h1 = f2bf(v.y), h2 = f2bf(v.z), h3 = f2bf(v.w);
            u16 l0 = f2bf(v.x - bf2f(h0)), l1 = f2bf(v.y - bf2f(h1));
            u16 l2 = f2bf(v.z - bf2f(h2)), l3 = f2bf(v.w - bf2f(h3));
            int off = (ge + 8 * q) * XS + gseg * 4;
            *(uint2*)&x_hi[off] = make_uint2((unsigned)h0 | ((unsigned)h1 << 16),
                                             (unsigned)h2 | ((unsigned)h3 << 16));
            *(uint2*)&x_lo[off] = make_uint2((unsigned)l0 | ((unsigned)l1 << 16),
                                             (unsigned)l2 | ((unsigned)l3 << 16));
        }
    };

    issue_gather(0);
    write_gather();
    __syncthreads();

    #pragma unroll
    for (int half = 0; half < 2; ++half) {
        const int arow0 = l31 * XS;
        const int arow1 = (32 + l31) * XS;
        const u16* bbase0 = w1t + (size_t)(wv * 64 + l31) * 512 + (half * 16 + q8) * 16;
        const u16* bbase1 = bbase0 + 32 * 512;
        if (half == 0) issue_gather(1);

        auto kstep = [&](int sl) {
            const int aoff = 16 * sl + 8 * q8;
            s8v ah0 = *(const s8v*)&x_hi[arow0 + aoff];
            s8v ah1 = *(const s8v*)&x_hi[arow1 + aoff];
            s8v al0 = *(const s8v*)&x_lo[arow0 + aoff];
            s8v al1 = *(const s8v*)&x_lo[arow1 + aoff];
            const u16* bp0 = bbase0 + sl * 32;
            const u16* bp1 = bbase1 + sl * 32;
            s8v bh0 = *(const s8v*)bp0;  s8v bl0 = *(const s8v*)(bp0 + 8);
            s8v bh1 = *(const s8v*)bp1;  s8v bl1 = *(const s8v*)(bp1 + 8);
            acc[0][0] = __builtin_amdgcn_mfma_f32_32x32x16_bf16(ah0, bh0, acc[0][0], 0, 0, 0);
            acc[0][0] = __builtin_amdgcn_mfma_f32_32x32x16_bf16(ah0, bl0, acc[0][0], 0, 0, 0);
            acc[0][0] = __builtin_amdgcn_mfma_f32_32x32x16_bf16(al0, bh0, acc[0][0], 0, 0, 0);
            acc[1][0] = __builtin_amdgcn_mfma_f32_32x32x16_bf16(ah1, bh0, acc[1][0], 0, 0, 0);
            acc[1][0] = __builtin_amdgcn_mfma_f32_32x32x16_bf16(ah1, bl0, acc[1][0], 0, 0, 0);
            acc[1][0] = __builtin_amdgcn_mfma_f32_32x32x16_bf16(al1, bh0, acc[1][0], 0, 0, 0);
            acc[0][1] = __builtin_amdgcn_mfma_f32_32x32x16_bf16(ah0, bh1, acc[0][1], 0, 0, 0);
            acc[0][1] = __builtin_amdgcn_mfma_f32_32x32x16_bf16(ah0, bl1, acc[0][1], 0, 0, 0);
            acc[0][1] = __builtin_amdgcn_mfma_f32_32x32x16_bf16(al0, bh1, acc[0][1], 0, 0, 0);
            acc[1][1] = __builtin_amdgcn_mfma_f32_32x32x16_bf16(ah1, bh1, acc[1][1], 0, 0, 0);
            acc[1][1] = __builtin_amdgcn_mfma_f32_32x32x16_bf16(ah1, bl1, acc[1][1], 0, 0, 0);
            acc[1][1] = __builtin_amdgcn_mfma_f32_32x32x16_bf16(al1, bh1, acc[1][1], 0, 0, 0);
        };

        kstep(0); kstep(1); kstep(2); kstep(3);
        kstep(4); kstep(5); kstep(6); kstep(7);

        if (half == 0) {
            __syncthreads();
            write_gather();
            __syncthreads();
        }
    }

    #pragma unroll
    for (int mt = 0; mt < 2; ++mt) {
        #pragma unroll
        for (int r = 0; r < 16; ++r) {
            float h0 = acc[mt][0][r] + b1v[0];
            float h1 = acc[mt][1][r] + b1v[1];
            float pp = (h0 > 0.f ? h0 : 0.f) * w2v[0] + (h1 > 0.f ? h1 : 0.f) * w2v[1];
            pp += __shfl_xor(pp, 1);  pp += __shfl_xor(pp, 2);
            pp += __shfl_xor(pp, 4);  pp += __shfl_xor(pp, 8);
            pp += __shfl_xor(pp, 16);
            if (l31 == 0)
                red[wv][mt * 32 + (r & 3) + 8 * (r >> 2) + 4 * q8] = pp;
        }
    }
    __syncthreads();

    if (tid < TE) {
        int eg = base + tid;
        if (eg < E) {
            float raw = red[0][tid] + red[1][tid] + red[2][tid] + red[3][tid] + b2s;
            out[eg] = (raw < T_SM) ? 0.f : raw;
            if (fabsf(raw - T_SM) < MARGIN_FB) {
                int pos = atomicAdd(count, 1);
                if (pos < cap) list[pos] = eg;
            }
        }
    }
}

extern "C" void kernel_launch(void* const* d_in, const int* in_sizes, int n_in,
                              void* d_out, int out_size, void* d_ws, size_t ws_size,
                              hipStream_t stream) {
    const float* emb = (const float*)d_in[0];
    const int*   ei  = (const int*)  d_in[1];
    const float* W1  = (const float*)d_in[2];
    const float* b1  = (const float*)d_in[3];
    const float* W2  = (const float*)d_in[4];
    const float* b2  = (const float*)d_in[5];
    float* out = (float*)d_out;
    const int E  = out_size;
    const int Nn = in_sizes[0] / 128;

    const size_t yBytes = (size_t)Nn * 512 * sizeof(_Float16);   // 102.4 MB @ N=100000
    const size_t fastNeed = yBytes + 262144 + 64 + 65536;

    if (ws_size >= fastNeed) {
        // fast path: factorized Y-table
        _Float16* Y = (_Float16*)d_ws;
        u16* w1tT  = (u16*)((char*)d_ws + yBytes);
        int* count = (int*)((char*)d_ws + yBytes + 262144);
        int* list  = (int*)((char*)d_ws + yBytes + 262208);
        int cap = (int)((ws_size - (yBytes + 262208)) / 4);
        if (cap > E) cap = E;

        hipLaunchKernelGGL(prep_kernelT, dim3(256), dim3(256), 0, stream, W1, w1tT, count);
        hipLaunchKernelGGL(gemm_y_kernel, dim3((Nn + TE - 1) / TE), dim3(THREADS), 0, stream,
                           emb, w1tT, Y, Nn);
        hipLaunchKernelGGL(edge_kernel, dim3(4096), dim3(256), 0, stream,
                           Y, ei, b1, W2, b2, out, count, list, cap, E);
        hipLaunchKernelGGL(fixup_tile_kernel, dim3(256), dim3(256), 0, stream,
                           emb, ei, W1, b1, W2, b2, count, list, out, E, cap);
    } else {
        // fallback: R5 fused edge-GEMM (proven)
        u16* w1t   = (u16*)d_ws;
        int* count = (int*)((char*)d_ws + 262144);
        int* list  = (int*)((char*)d_ws + 262208);
        long avail = (long)ws_size - 262208;
        int cap = (avail > 4) ? (int)(avail / 4) : 0;
        if (cap > E) cap = E;

        hipLaunchKernelGGL(prep_kernel, dim3(256), dim3(256), 0, stream, W1, w1t, count);
        hipLaunchKernelGGL(linkmlp_mfma, dim3((E + TE - 1) / TE), dim3(THREADS), 0, stream,
                           emb, ei, w1t, b1, W2, b2, out, count, list, cap, E);
        hipLaunchKernelGGL(fixup_tile_kernel, dim3(256), dim3(256), 0, stream,
                           emb, ei, W1, b1, W2, b2, count, list, out, E, cap);
    }
}